// Round 2
// baseline (647.744 us; speedup 1.0000x reference)
//
#include <hip/hip_runtime.h>
#include <hip/hip_bf16.h>

#define T_TOKENS 4096
#define D_MODEL  1024
#define N_EXP    16
#define D_FF     1024
#define D_FF_SH  2048
#define MAX_T256 48   // sum ceil(count_e/256) <= 8192/256 + 16 = 48

typedef __attribute__((ext_vector_type(8))) short short8;
typedef __attribute__((ext_vector_type(4))) float float4v;

__device__ __forceinline__ short f2bf(float f) {
    union { float f; unsigned u; } c; c.f = f;
    unsigned u = c.u + 0x7fffu + ((c.u >> 16) & 1u);
    return (short)(u >> 16);
}

// async global->LDS, 16B per lane; LDS dest = wave-uniform base + lane*16.
__device__ __forceinline__ void gload16(const void* g, void* l) {
    __builtin_amdgcn_global_load_lds(
        (const __attribute__((address_space(1))) void*)g,
        (__attribute__((address_space(3))) void*)l, 16, 0, 0);
}

// counted-vmcnt ring step top: drain own slice-k loads + own LDS reads, then barrier.
#define RING_TOP(VM) do { \
    asm volatile("s_waitcnt vmcnt(" #VM ") lgkmcnt(0)" ::: "memory"); \
    __builtin_amdgcn_s_barrier(); \
} while (0)

// ---------------------------------------------------------------- convert (all 4 weights, one dispatch)
__global__ __launch_bounds__(256) void convert_all_kernel(
    const float* __restrict__ s0, short* __restrict__ d0,   // egu   33554432
    const float* __restrict__ s1, short* __restrict__ d1,   // edown 16777216
    const float* __restrict__ s2, short* __restrict__ d2,   // sgu    4194304
    const float* __restrict__ s3, short* __restrict__ d3) { // sdown  2097152
    int c = blockIdx.x * 256 + threadIdx.x;   // chunk of 8 elements
    const float* s; short* d; int off;
    if      (c < 4194304) { s = s0; d = d0; off = c; }
    else if (c < 6291456) { s = s1; d = d1; off = c - 4194304; }
    else if (c < 6815744) { s = s2; d = d2; off = c - 6291456; }
    else                  { s = s3; d = d3; off = c - 6815744; }
    size_t i = (size_t)off * 8;
    float4 a = *(const float4*)(s + i);
    float4 b = *(const float4*)(s + i + 4);
    union { short sh[8]; int4 v; } p;
    p.sh[0] = f2bf(a.x); p.sh[1] = f2bf(a.y); p.sh[2] = f2bf(a.z); p.sh[3] = f2bf(a.w);
    p.sh[4] = f2bf(b.x); p.sh[5] = f2bf(b.y); p.sh[6] = f2bf(b.z); p.sh[7] = f2bf(b.w);
    *(int4*)(d + i) = p.v;
}

// ---------------------------------------------------------------- router (fp32 exact, LDS-staged weights)
__global__ __launch_bounds__(256) void router_kernel(
    const float* __restrict__ x, const float* __restrict__ gw, const float* __restrict__ sgw,
    short* __restrict__ xb, int* __restrict__ topk_id, float* __restrict__ topk_w,
    float* __restrict__ gate, int* __restrict__ counts) {
    __shared__ float gwl[17 * 1024];   // 69632 B
    int tid = threadIdx.x;
#pragma unroll
    for (int i = 0; i < 16; i++)
        *(float4*)&gwl[tid * 4 + i * 1024] = *(const float4*)&gw[tid * 4 + i * 1024];
    *(float4*)&gwl[16384 + tid * 4] = *(const float4*)&sgw[tid * 4];
    __syncthreads();

    int wave = tid >> 6, lane = tid & 63;
    int t0 = blockIdx.x * 16 + wave * 4;

    float acc[4][17];
#pragma unroll
    for (int tt = 0; tt < 4; tt++)
#pragma unroll
        for (int e = 0; e < 17; e++) acc[tt][e] = 0.f;

#pragma unroll
    for (int i = 0; i < 4; i++) {
        int d = lane * 4 + i * 256;
        float4 xv[4];
#pragma unroll
        for (int tt = 0; tt < 4; tt++) {
            xv[tt] = *(const float4*)&x[(size_t)(t0 + tt) * D_MODEL + d];
            union { short sh[4]; int2 v; } p;
            p.sh[0] = f2bf(xv[tt].x); p.sh[1] = f2bf(xv[tt].y);
            p.sh[2] = f2bf(xv[tt].z); p.sh[3] = f2bf(xv[tt].w);
            *(int2*)&xb[(size_t)(t0 + tt) * D_MODEL + d] = p.v;
        }
#pragma unroll
        for (int e = 0; e < 17; e++) {
            float4 g = *(const float4*)&gwl[e * 1024 + d];
#pragma unroll
            for (int tt = 0; tt < 4; tt++)
                acc[tt][e] += xv[tt].x * g.x + xv[tt].y * g.y + xv[tt].z * g.z + xv[tt].w * g.w;
        }
    }

#pragma unroll
    for (int tt = 0; tt < 4; tt++)
#pragma unroll
        for (int e = 0; e < 17; e++)
            for (int off = 32; off; off >>= 1) acc[tt][e] += __shfl_xor(acc[tt][e], off);

    if (lane == 0) {
#pragma unroll
        for (int tt = 0; tt < 4; tt++) {
            int t = t0 + tt;
            float v1 = -1e30f, v2 = -1e30f; int i1 = 0, i2 = 0;
#pragma unroll
            for (int e = 0; e < 16; e++) {
                float v = acc[tt][e];
                if (v > v1) { v2 = v1; i2 = i1; v1 = v; i1 = e; }
                else if (v > v2) { v2 = v; i2 = e; }
            }
            float e2 = expf(v2 - v1);
            float s = 1.f + e2;
            topk_id[t * 2] = i1; topk_id[t * 2 + 1] = i2;
            topk_w[t * 2] = 1.f / s; topk_w[t * 2 + 1] = e2 / s;
            gate[t] = 1.f / (1.f + expf(-acc[tt][16]));
            atomicAdd(&counts[i1], 1); atomicAdd(&counts[i2], 1);
        }
    }
}

// ---------------------------------------------------------------- offsets + live 256-row-tile map
__global__ void offsets_kernel(const int* __restrict__ counts, int* __restrict__ offsets,
                               int* __restrict__ cursor, int* __restrict__ tile_map,
                               int* __restrict__ n_tiles, int* __restrict__ gc) {
    if (threadIdx.x == 0) {
        int off = 0, nt = 0;
        for (int e = 0; e < N_EXP; e++) {
            offsets[e] = off; cursor[e] = off;
            int c = counts[e];
            for (int r = 0; r < c; r += 256) tile_map[nt++] = (e << 16) | (r >> 8);
            off += c;
        }
        n_tiles[0] = nt;
        gc[0] = 0; gc[1] = 0;   // work-stealing counters for gemm1/gemm2
    }
}

__global__ __launch_bounds__(256) void scatter_kernel(
    const int* __restrict__ topk_id, const float* __restrict__ topk_w,
    int* __restrict__ cursor, int* __restrict__ tok_list, float* __restrict__ tok_w,
    int* __restrict__ slot_of) {
    int t = blockIdx.x * 256 + threadIdx.x;
#pragma unroll
    for (int k = 0; k < 2; k++) {
        int e = topk_id[t * 2 + k];
        int pos = atomicAdd(&cursor[e], 1);
        tok_list[pos] = t;
        tok_w[pos] = topk_w[t * 2 + k];
        slot_of[t * 2 + k] = pos;
    }
}

// ---------------------------------------------------------------- GEMM1: persistent blocks, 256x128 tile, fused gate+up
// 256 blocks (1/CU, co-resident), tile via work-stealing atomic. Ring-4 of BK=32 slices
// (32KB each), depth-3 prefetch, counted vmcnt. Chunk-rotation swizzle (conflict-free, verified R1).
__global__ __launch_bounds__(512, 2) void gemm1_kernel(
    const short* __restrict__ xb,
    const short* __restrict__ Wexp,   // [16][2048][1024]
    const short* __restrict__ Wsh,    // [4096][1024]
    short* __restrict__ Hexp,         // [8192][1024]
    short* __restrict__ Hsh,          // [4096][2048]
    const int* __restrict__ tok_list,
    const int* __restrict__ offsets, const int* __restrict__ counts,
    const int* __restrict__ tile_map, const int* __restrict__ n_tiles,
    int* __restrict__ gc) {
    __shared__ char lds[131072];   // 4 ring slices x 32KB
    __shared__ int s_tile;

    int t = threadIdx.x;
    int wave = t >> 6, lane = t & 63;
    int wm = (wave & 3) * 64, wn = (wave >> 2) * 64;
    int fr = lane & 15;
    int fk2p = ((((lane >> 4) + (fr >> 1)) & 3) << 4);
    int rA = t >> 2;                      // 0..127
    int csrc = ((t & 3) - (t >> 3)) & 3;  // inverse-rotated source chunk
    int cq = csrc * 8;                    // shorts
    int lo = t * 16;                      // linear LDS dest

    int nt = n_tiles[0];
    int total = 256 + nt * 8;             // shared tiles first (id<256), then expert

    for (;;) {
        if (t == 0) s_tile = atomicAdd(gc, 1);
        __syncthreads();                  // broadcast + inter-tile LDS hazard barrier
        int id = s_tile;
        if (id >= total) return;

        int count, row0, dff, col0;
        const int* idx = nullptr;
        const short* Wg; short* Hout;
        if (id < 256) {
            row0 = (id >> 4) * 256; count = T_TOKENS;
            Wg = Wsh; Hout = Hsh; dff = D_FF_SH; col0 = (id & 15) * 128;
        } else {
            int q = id - 256;
            int tm = tile_map[q >> 3];
            int e = tm >> 16; row0 = (tm & 0xffff) << 8;
            count = counts[e];
            int base = offsets[e];
            idx = tok_list + base;
            Wg = Wexp + (size_t)e * 2 * D_FF * D_MODEL;
            Hout = Hexp + (size_t)base * D_FF;
            dff = D_FF;
            col0 = (q & 7) * 128;
        }
        const short* Wu = Wg + (size_t)dff * D_MODEL;

        int r0c = min(row0 + rA, count - 1);
        int r1c = min(row0 + rA + 128, count - 1);
        int g0 = idx ? idx[r0c] : r0c;
        int g1 = idx ? idx[r1c] : r1c;
        const short* aP0 = xb + (size_t)g0 * D_MODEL + cq;
        const short* aP1 = xb + (size_t)g1 * D_MODEL + cq;
        const short* bgP = Wg + (size_t)(col0 + rA) * D_MODEL + cq;
        const short* buP = Wu + (size_t)(col0 + rA) * D_MODEL + cq;

        float4v accg[4][4], accu[4][4];
#pragma unroll
        for (int i = 0; i < 4; i++)
#pragma unroll
            for (int j = 0; j < 4; j++) { accg[i][j] = (float4v)0.f; accu[i][j] = (float4v)0.f; }

        auto stage = [&](int s) {
            char* base = lds + (s & 3) * 32768;
            int off = s * 32;                 // shorts
            gload16(aP0 + off, base + lo);
            gload16(aP1 + off, base + 8192 + lo);
            gload16(bgP + off, base + 16384 + lo);
            gload16(buP + off, base + 24576 + lo);
        };
        auto compute = [&](int k) {
            const char* sb = lds + (k & 3) * 32768;
            short8 af[4], bgf[4], buf4[4];
#pragma unroll
            for (int i = 0; i < 4; i++)
                af[i] = *(const short8*)(sb + (wm + i * 16 + fr) * 64 + fk2p);
#pragma unroll
            for (int j = 0; j < 4; j++) {
                bgf[j] = *(const short8*)(sb + 16384 + (wn + j * 16 + fr) * 64 + fk2p);
                buf4[j] = *(const short8*)(sb + 24576 + (wn + j * 16 + fr) * 64 + fk2p);
            }
            __builtin_amdgcn_s_setprio(1);
#pragma unroll
            for (int i = 0; i < 4; i++)
#pragma unroll
                for (int j = 0; j < 4; j++) {
                    accg[i][j] = __builtin_amdgcn_mfma_f32_16x16x32_bf16(af[i], bgf[j], accg[i][j], 0, 0, 0);
                    accu[i][j] = __builtin_amdgcn_mfma_f32_16x16x32_bf16(af[i], buf4[j], accu[i][j], 0, 0, 0);
                }
            __builtin_amdgcn_s_setprio(0);
        };

        const int NK = D_MODEL / 32;  // 32 slices
        stage(0); stage(1); stage(2);
        int k = 0;
        for (; k < NK - 3; ++k) {
            RING_TOP(8);                 // slice k landed (4 loads/slice, 3 slices in flight)
            stage(k + 3);
            compute(k);
        }
        RING_TOP(8); compute(k); ++k;    // NK-3
        RING_TOP(4); compute(k); ++k;    // NK-2
        RING_TOP(0); compute(k);         // NK-1

        int erow = (lane >> 4) * 4;
        int ecol = lane & 15;
#pragma unroll
        for (int i = 0; i < 4; i++)
#pragma unroll
            for (int j = 0; j < 4; j++)
#pragma unroll
                for (int r = 0; r < 4; r++) {
                    int row = wm + i * 16 + erow + r;
                    if (row0 + row < count) {
                        float g = accg[i][j][r], u = accu[i][j][r];
                        float h = g / (1.f + expf(-g)) * u;
                        Hout[(size_t)(row0 + row) * dff + col0 + wn + j * 16 + ecol] = f2bf(h);
                    }
                }
    }
}

// ---------------------------------------------------------------- GEMM2: persistent blocks, 256x128 tile
// 256 blocks, work-stealing; shared (K=2048, longest) tiles handed out first.
// Ring-6 of BK=32 slices (24KB each), depth-5 prefetch, counted vmcnt. Same swizzle.
__global__ __launch_bounds__(512, 2) void gemm2_kernel(
    const short* __restrict__ Hexp, const short* __restrict__ Hsh,
    const short* __restrict__ Wdexp,  // [16][1024][1024]
    const short* __restrict__ Wdsh,   // [1024][2048]
    float* __restrict__ oslots,       // [8192][1024]
    float* __restrict__ out,          // [4096][1024]
    const float* __restrict__ tok_w, const float* __restrict__ gate,
    const int* __restrict__ offsets, const int* __restrict__ counts,
    const int* __restrict__ tile_map, const int* __restrict__ n_tiles,
    int* __restrict__ gc) {
    __shared__ char lds[147456];   // 6 ring slices x 24KB
    __shared__ int s_tile;

    int t = threadIdx.x;
    int wave = t >> 6, lane = t & 63;
    int wm = (wave & 3) * 64, wn = (wave >> 2) * 64;
    int fr = lane & 15;
    int fk2p = ((((lane >> 4) + (fr >> 1)) & 3) << 4);
    int rA = t >> 2;
    int csrc = ((t & 3) - (t >> 3)) & 3;
    int cq = csrc * 8;
    int lo = t * 16;

    int nt = n_tiles[0];
    int total = 128 + nt * 8;             // shared (long-K) tiles first

    for (;;) {
        if (t == 0) s_tile = atomicAdd(gc, 1);
        __syncthreads();
        int id = s_tile;
        if (id >= total) return;

        int count, row0, K, base, col0;
        const short* Ab; const short* B;
        bool shared_part;
        if (id < 128) {
            row0 = (id >> 3) * 256; count = T_TOKENS; base = 0;
            Ab = Hsh; K = D_FF_SH; B = Wdsh; shared_part = true;
            col0 = (id & 7) * 128;
        } else {
            int q = id - 128;
            int tm = tile_map[q >> 3];
            int e = tm >> 16; row0 = (tm & 0xffff) << 8;
            count = counts[e]; base = offsets[e];
            Ab = Hexp + (size_t)base * D_FF; K = D_FF;
            B = Wdexp + (size_t)e * D_MODEL * D_FF;
            shared_part = false;
            col0 = (q & 7) * 128;
        }

        int r0c = min(row0 + rA, count - 1);
        int r1c = min(row0 + rA + 128, count - 1);
        const short* aP0 = Ab + (size_t)r0c * K + cq;
        const short* aP1 = Ab + (size_t)r1c * K + cq;
        const short* bP  = B + (size_t)(col0 + rA) * K + cq;

        float4v acc[4][4];
#pragma unroll
        for (int i = 0; i < 4; i++)
#pragma unroll
            for (int j = 0; j < 4; j++) acc[i][j] = (float4v)0.f;

        auto stage = [&](int pos, int s) {
            char* bb = lds + pos * 24576;
            int off = s * 32;
            gload16(aP0 + off, bb + lo);
            gload16(aP1 + off, bb + 8192 + lo);
            gload16(bP + off,  bb + 16384 + lo);
        };
        auto compute = [&](int pos) {
            const char* sb = lds + pos * 24576;
            short8 af[4], bf[4];
#pragma unroll
            for (int i = 0; i < 4; i++)
                af[i] = *(const short8*)(sb + (wm + i * 16 + fr) * 64 + fk2p);
#pragma unroll
            for (int j = 0; j < 4; j++)
                bf[j] = *(const short8*)(sb + 16384 + (wn + j * 16 + fr) * 64 + fk2p);
            __builtin_amdgcn_s_setprio(1);
#pragma unroll
            for (int i = 0; i < 4; i++)
#pragma unroll
                for (int j = 0; j < 4; j++)
                    acc[i][j] = __builtin_amdgcn_mfma_f32_16x16x32_bf16(af[i], bf[j], acc[i][j], 0, 0, 0);
            __builtin_amdgcn_s_setprio(0);
        };

        const int NK = K / 32;        // 32 or 64
        stage(0, 0); stage(1, 1); stage(2, 2); stage(3, 3); stage(4, 4);
        int k = 0, spos = 5, cpos = 0;
        for (; k < NK - 5; ++k) {
            RING_TOP(12);              // slice k landed (3 loads/slice, 5 slices in flight)
            stage(spos, k + 5); spos = (spos == 5) ? 0 : spos + 1;
            compute(cpos);      cpos = (cpos == 5) ? 0 : cpos + 1;
        }
        RING_TOP(12); compute(cpos); cpos = (cpos == 5) ? 0 : cpos + 1; ++k;
        RING_TOP(9);  compute(cpos); cpos = (cpos == 5) ? 0 : cpos + 1; ++k;
        RING_TOP(6);  compute(cpos); cpos = (cpos == 5) ? 0 : cpos + 1; ++k;
        RING_TOP(3);  compute(cpos); cpos = (cpos == 5) ? 0 : cpos + 1; ++k;
        RING_TOP(0);  compute(cpos);

        int erow = (lane >> 4) * 4;
        int ecol = lane & 15;
#pragma unroll
        for (int i = 0; i < 4; i++)
#pragma unroll
            for (int j = 0; j < 4; j++)
#pragma unroll
                for (int r = 0; r < 4; r++) {
                    int row = wm + i * 16 + erow + r;
                    if (row0 + row < count) {
                        float v = acc[i][j][r];
                        int col = col0 + wn + j * 16 + ecol;
                        if (!shared_part) {
                            int slot = base + row0 + row;
                            oslots[(size_t)slot * D_MODEL + col] = tok_w[slot] * v;
                        } else {
                            out[(size_t)(row0 + row) * D_MODEL + col] = gate[row0 + row] * v;
                        }
                    }
                }
    }
}

// ---------------------------------------------------------------- combine: out[t] += oslots[sA] + oslots[sB]
__global__ __launch_bounds__(256) void combine_kernel(
    float* __restrict__ out, const float* __restrict__ oslots,
    const int* __restrict__ slot_of) {
    int t = blockIdx.x;
    int sA = slot_of[t * 2], sB = slot_of[t * 2 + 1];
    int d = threadIdx.x * 4;
    float4 o = *(float4*)&out[(size_t)t * D_MODEL + d];
    float4 a = *(const float4*)&oslots[(size_t)sA * D_MODEL + d];
    float4 b = *(const float4*)&oslots[(size_t)sB * D_MODEL + d];
    o.x += a.x + b.x; o.y += a.y + b.y; o.z += a.z + b.z; o.w += a.w + b.w;
    *(float4*)&out[(size_t)t * D_MODEL + d] = o;
}

// ---------------------------------------------------------------- host
extern "C" void kernel_launch(void* const* d_in, const int* in_sizes, int n_in,
                              void* d_out, int out_size, void* d_ws, size_t ws_size,
                              hipStream_t stream) {
    const float* x     = (const float*)d_in[0];
    const float* gw    = (const float*)d_in[1];
    const float* egu   = (const float*)d_in[2];
    const float* edown = (const float*)d_in[3];
    const float* sgu   = (const float*)d_in[4];
    const float* sdown = (const float*)d_in[5];
    const float* sgate = (const float*)d_in[6];
    float* out = (float*)d_out;
    char* ws = (char*)d_ws;

    const size_t XB_OFF     = 0;
    const size_t WGU_OFF    = XB_OFF     + (size_t)4096*1024*2;
    const size_t WDOWN_OFF  = WGU_OFF    + (size_t)16*2048*1024*2;
    const size_t WSGU_OFF   = WDOWN_OFF  + (size_t)16*1024*1024*2;
    const size_t WSDOWN_OFF = WSGU_OFF   + (size_t)4096*1024*2;
    const size_t HEXP_OFF   = WSDOWN_OFF + (size_t)1024*2048*2;
    const size_t HSH_OFF    = HEXP_OFF   + (size_t)8192*1024*2;
    const size_t OSLOT_OFF  = HSH_OFF    + (size_t)4096*2048*2;
    const size_t TID_OFF    = OSLOT_OFF  + (size_t)8192*1024*4;
    const size_t TW_OFF     = TID_OFF    + 4096*2*4;
    const size_t GATE_OFF   = TW_OFF     + 4096*2*4;
    const size_t TOKL_OFF   = GATE_OFF   + 4096*4;
    const size_t TOKW_OFF   = TOKL_OFF   + 8192*4;
    const size_t SLOT_OFF   = TOKW_OFF   + 8192*4;
    const size_t CNT_OFF    = SLOT_OFF   + 8192*4;
    const size_t OFFS_OFF   = CNT_OFF    + 256;
    const size_t CUR_OFF    = OFFS_OFF   + 256;
    const size_t TMAP_OFF   = CUR_OFF    + 256;
    const size_t NT_OFF     = TMAP_OFF   + 512;
    const size_t GC_OFF     = NT_OFF     + 16;

    short* xb      = (short*)(ws + XB_OFF);
    short* wgu_b   = (short*)(ws + WGU_OFF);
    short* wdown_b = (short*)(ws + WDOWN_OFF);
    short* wsgu_b  = (short*)(ws + WSGU_OFF);
    short* wsdn_b  = (short*)(ws + WSDOWN_OFF);
    short* h_exp   = (short*)(ws + HEXP_OFF);
    short* h_sh    = (short*)(ws + HSH_OFF);
    float* oslots  = (float*)(ws + OSLOT_OFF);
    int*   topk_id = (int*)(ws + TID_OFF);
    float* topk_w  = (float*)(ws + TW_OFF);
    float* gate    = (float*)(ws + GATE_OFF);
    int*   tok_l   = (int*)(ws + TOKL_OFF);
    float* tok_w   = (float*)(ws + TOKW_OFF);
    int*   slot_of = (int*)(ws + SLOT_OFF);
    int*   counts  = (int*)(ws + CNT_OFF);
    int*   offsets = (int*)(ws + OFFS_OFF);
    int*   cursor  = (int*)(ws + CUR_OFF);
    int*   tmap    = (int*)(ws + TMAP_OFF);
    int*   ntiles  = (int*)(ws + NT_OFF);
    int*   gcnt    = (int*)(ws + GC_OFF);

    hipMemsetAsync(counts, 0, 64, stream);

    convert_all_kernel<<<27648, 256, 0, stream>>>(egu, wgu_b, edown, wdown_b,
                                                  sgu, wsgu_b, sdown, wsdn_b);
    router_kernel<<<256, 256, 0, stream>>>(x, gw, sgate, xb, topk_id, topk_w, gate, counts);
    offsets_kernel<<<1, 64, 0, stream>>>(counts, offsets, cursor, tmap, ntiles, gcnt);
    scatter_kernel<<<T_TOKENS / 256, 256, 0, stream>>>(topk_id, topk_w, cursor, tok_l, tok_w, slot_of);

    gemm1_kernel<<<256, 512, 0, stream>>>(
        xb, wgu_b, wsgu_b, h_exp, h_sh, tok_l, offsets, counts, tmap, ntiles, gcnt);

    gemm2_kernel<<<256, 512, 0, stream>>>(
        h_exp, h_sh, wdown_b, wsdn_b, oslots, out, tok_w, gate, offsets, counts, tmap, ntiles, gcnt + 1);

    combine_kernel<<<T_TOKENS, 256, 0, stream>>>(out, oslots, slot_of);
}

// Round 3
// 592.974 us; speedup vs baseline: 1.0924x; 1.0924x over previous
//
#include <hip/hip_runtime.h>
#include <hip/hip_bf16.h>

#define T_TOKENS 4096
#define D_MODEL  1024
#define N_EXP    16
#define D_FF     1024
#define D_FF_SH  2048
#define MAX_T256 48   // sum ceil(count_e/256) <= 8192/256 + 16 = 48

typedef __attribute__((ext_vector_type(8))) short short8;
typedef __attribute__((ext_vector_type(4))) float float4v;

__device__ __forceinline__ short f2bf(float f) {
    union { float f; unsigned u; } c; c.f = f;
    unsigned u = c.u + 0x7fffu + ((c.u >> 16) & 1u);
    return (short)(u >> 16);
}

// async global->LDS, 16B per lane; LDS dest = wave-uniform base + lane*16.
__device__ __forceinline__ void gload16(const void* g, void* l) {
    __builtin_amdgcn_global_load_lds(
        (const __attribute__((address_space(1))) void*)g,
        (__attribute__((address_space(3))) void*)l, 16, 0, 0);
}

// counted-vmcnt ring step top: drain own slice-k loads + own LDS reads, then barrier.
#define RING_TOP(VM) do { \
    asm volatile("s_waitcnt vmcnt(" #VM ") lgkmcnt(0)" ::: "memory"); \
    __builtin_amdgcn_s_barrier(); \
} while (0)

// phase rendezvous: raw barrier (no waitcnt drain) + full scheduling fence so the
// compiler can neither sink ds_reads below nor hoist MFMAs above (rule #18).
#define PHASE_BAR() do { \
    asm volatile("s_barrier" ::: "memory"); \
    __builtin_amdgcn_sched_barrier(0); \
} while (0)

// ---------------------------------------------------------------- convert (all 4 weights, one dispatch)
__global__ __launch_bounds__(256) void convert_all_kernel(
    const float* __restrict__ s0, short* __restrict__ d0,   // egu   33554432
    const float* __restrict__ s1, short* __restrict__ d1,   // edown 16777216
    const float* __restrict__ s2, short* __restrict__ d2,   // sgu    4194304
    const float* __restrict__ s3, short* __restrict__ d3) { // sdown  2097152
    int c = blockIdx.x * 256 + threadIdx.x;   // chunk of 8 elements
    const float* s; short* d; int off;
    if      (c < 4194304) { s = s0; d = d0; off = c; }
    else if (c < 6291456) { s = s1; d = d1; off = c - 4194304; }
    else if (c < 6815744) { s = s2; d = d2; off = c - 6291456; }
    else                  { s = s3; d = d3; off = c - 6815744; }
    size_t i = (size_t)off * 8;
    float4 a = *(const float4*)(s + i);
    float4 b = *(const float4*)(s + i + 4);
    union { short sh[8]; int4 v; } p;
    p.sh[0] = f2bf(a.x); p.sh[1] = f2bf(a.y); p.sh[2] = f2bf(a.z); p.sh[3] = f2bf(a.w);
    p.sh[4] = f2bf(b.x); p.sh[5] = f2bf(b.y); p.sh[6] = f2bf(b.z); p.sh[7] = f2bf(b.w);
    *(int4*)(d + i) = p.v;
}

// ---------------------------------------------------------------- router (fp32 exact, LDS-staged weights)
__global__ __launch_bounds__(256) void router_kernel(
    const float* __restrict__ x, const float* __restrict__ gw, const float* __restrict__ sgw,
    short* __restrict__ xb, int* __restrict__ topk_id, float* __restrict__ topk_w,
    float* __restrict__ gate, int* __restrict__ counts) {
    __shared__ float gwl[17 * 1024];   // 69632 B
    int tid = threadIdx.x;
#pragma unroll
    for (int i = 0; i < 16; i++)
        *(float4*)&gwl[tid * 4 + i * 1024] = *(const float4*)&gw[tid * 4 + i * 1024];
    *(float4*)&gwl[16384 + tid * 4] = *(const float4*)&sgw[tid * 4];
    __syncthreads();

    int wave = tid >> 6, lane = tid & 63;
    int t0 = blockIdx.x * 16 + wave * 4;

    float acc[4][17];
#pragma unroll
    for (int tt = 0; tt < 4; tt++)
#pragma unroll
        for (int e = 0; e < 17; e++) acc[tt][e] = 0.f;

#pragma unroll
    for (int i = 0; i < 4; i++) {
        int d = lane * 4 + i * 256;
        float4 xv[4];
#pragma unroll
        for (int tt = 0; tt < 4; tt++) {
            xv[tt] = *(const float4*)&x[(size_t)(t0 + tt) * D_MODEL + d];
            union { short sh[4]; int2 v; } p;
            p.sh[0] = f2bf(xv[tt].x); p.sh[1] = f2bf(xv[tt].y);
            p.sh[2] = f2bf(xv[tt].z); p.sh[3] = f2bf(xv[tt].w);
            *(int2*)&xb[(size_t)(t0 + tt) * D_MODEL + d] = p.v;
        }
#pragma unroll
        for (int e = 0; e < 17; e++) {
            float4 g = *(const float4*)&gwl[e * 1024 + d];
#pragma unroll
            for (int tt = 0; tt < 4; tt++)
                acc[tt][e] += xv[tt].x * g.x + xv[tt].y * g.y + xv[tt].z * g.z + xv[tt].w * g.w;
        }
    }

#pragma unroll
    for (int tt = 0; tt < 4; tt++)
#pragma unroll
        for (int e = 0; e < 17; e++)
            for (int off = 32; off; off >>= 1) acc[tt][e] += __shfl_xor(acc[tt][e], off);

    if (lane == 0) {
#pragma unroll
        for (int tt = 0; tt < 4; tt++) {
            int t = t0 + tt;
            float v1 = -1e30f, v2 = -1e30f; int i1 = 0, i2 = 0;
#pragma unroll
            for (int e = 0; e < 16; e++) {
                float v = acc[tt][e];
                if (v > v1) { v2 = v1; i2 = i1; v1 = v; i1 = e; }
                else if (v > v2) { v2 = v; i2 = e; }
            }
            float e2 = expf(v2 - v1);
            float s = 1.f + e2;
            topk_id[t * 2] = i1; topk_id[t * 2 + 1] = i2;
            topk_w[t * 2] = 1.f / s; topk_w[t * 2 + 1] = e2 / s;
            gate[t] = 1.f / (1.f + expf(-acc[tt][16]));
            atomicAdd(&counts[i1], 1); atomicAdd(&counts[i2], 1);
        }
    }
}

// ---------------------------------------------------------------- offsets + live 256-row-tile map
__global__ void offsets_kernel(const int* __restrict__ counts, int* __restrict__ offsets,
                               int* __restrict__ cursor, int* __restrict__ tile_map,
                               int* __restrict__ n_tiles) {
    if (threadIdx.x == 0) {
        int off = 0, nt = 0;
        for (int e = 0; e < N_EXP; e++) {
            offsets[e] = off; cursor[e] = off;
            int c = counts[e];
            for (int r = 0; r < c; r += 256) tile_map[nt++] = (e << 16) | (r >> 8);
            off += c;
        }
        n_tiles[0] = nt;
    }
}

__global__ __launch_bounds__(256) void scatter_kernel(
    const int* __restrict__ topk_id, const float* __restrict__ topk_w,
    int* __restrict__ cursor, int* __restrict__ tok_list, float* __restrict__ tok_w,
    int* __restrict__ slot_of) {
    int t = blockIdx.x * 256 + threadIdx.x;
#pragma unroll
    for (int k = 0; k < 2; k++) {
        int e = topk_id[t * 2 + k];
        int pos = atomicAdd(&cursor[e], 1);
        tok_list[pos] = t;
        tok_w[pos] = topk_w[t * 2 + k];
        slot_of[t * 2 + k] = pos;
    }
}

// ---------------------------------------------------------------- GEMM1: 256x(128g+128u) tile, 2-phase interleave
// grid (80,8): bx<48 expert tile-row (by=col 0..7); bx 48..79 -> shared id=(bx-48)*8+by (256 tiles).
// Ring-4 of BK=32 slices (32KB: A16K|Bg8K|Bu8K), depth-3 prefetch, counted vmcnt.
// Each K-step = 2 phases: {stage A-pair, read af/bgf, BAR, 16 MFMA accg} then
// {stage B-pair, read buf, BAR, 16 MFMA accu} — fine interleave for wave role-split (T3/T5).
// Chunk-rotation swizzle (conflict-free, verified: SQ_LDS_BANK_CONFLICT=0).
__global__ __launch_bounds__(512, 2) void gemm1_kernel(
    const short* __restrict__ xb,
    const short* __restrict__ Wexp,   // [16][2048][1024]
    const short* __restrict__ Wsh,    // [4096][1024]
    short* __restrict__ Hexp,         // [8192][1024]
    short* __restrict__ Hsh,          // [4096][2048]
    const int* __restrict__ tok_list,
    const int* __restrict__ offsets, const int* __restrict__ counts,
    const int* __restrict__ tile_map, const int* __restrict__ n_tiles) {
    int bx = blockIdx.x, by = blockIdx.y;
    int count, row0, dff, col0;
    const int* idx = nullptr;
    const short* Wg; short* Hout;
    if (bx < MAX_T256) {
        if (bx >= n_tiles[0]) return;
        int tm = tile_map[bx];
        int e = tm >> 16; row0 = (tm & 0xffff) << 8;
        count = counts[e];
        int base = offsets[e];
        idx = tok_list + base;
        Wg = Wexp + (size_t)e * 2 * D_FF * D_MODEL;
        Hout = Hexp + (size_t)base * D_FF;
        dff = D_FF;
        col0 = by * 128;
    } else {
        int id = (bx - MAX_T256) * 8 + by;   // 0..255
        row0 = (id >> 4) * 256; count = T_TOKENS;
        Wg = Wsh; Hout = Hsh; dff = D_FF_SH;
        col0 = (id & 15) * 128;
    }
    const short* Wu = Wg + (size_t)dff * D_MODEL;

    __shared__ char lds[131072];   // 4 ring slices x 32KB

    int t = threadIdx.x;
    int wave = t >> 6, lane = t & 63;
    int wm = (wave & 3) * 64, wn = (wave >> 2) * 64;
    int fr = lane & 15;
    int fk2p = ((((lane >> 4) + (fr >> 1)) & 3) << 4);   // rotated read chunk
    int rA = t >> 2;                      // 0..127
    int csrc = ((t & 3) - (t >> 3)) & 3;  // inverse-rotated source chunk
    int cq = csrc * 8;                    // shorts
    int lo = t * 16;                      // linear LDS dest

    int r0c = min(row0 + rA, count - 1);
    int r1c = min(row0 + rA + 128, count - 1);
    int g0 = idx ? idx[r0c] : r0c;
    int g1 = idx ? idx[r1c] : r1c;
    const short* aP0 = xb + (size_t)g0 * D_MODEL + cq;
    const short* aP1 = xb + (size_t)g1 * D_MODEL + cq;
    const short* bgP = Wg + (size_t)(col0 + rA) * D_MODEL + cq;
    const short* buP = Wu + (size_t)(col0 + rA) * D_MODEL + cq;

    float4v accg[4][4], accu[4][4];
#pragma unroll
    for (int i = 0; i < 4; i++)
#pragma unroll
        for (int j = 0; j < 4; j++) { accg[i][j] = (float4v)0.f; accu[i][j] = (float4v)0.f; }

    auto stage = [&](int s) {
        char* base = lds + (s & 3) * 32768;
        int off = s * 32;                 // shorts
        gload16(aP0 + off, base + lo);
        gload16(aP1 + off, base + 8192 + lo);
        gload16(bgP + off, base + 16384 + lo);
        gload16(buP + off, base + 24576 + lo);
    };

    auto step = [&](int k, bool pf) {
        const char* sb = lds + (k & 3) * 32768;
        char* nb = lds + ((k + 3) & 3) * 32768;
        int off3 = (k + 3) * 32;
        // ---- phase A: stage A-pair of slice k+3, read af+bgf of slice k
        if (pf) { gload16(aP0 + off3, nb + lo); gload16(aP1 + off3, nb + 8192 + lo); }
        short8 af[4], bgf[4];
#pragma unroll
        for (int i = 0; i < 4; i++)
            af[i] = *(const short8*)(sb + (wm + i * 16 + fr) * 64 + fk2p);
#pragma unroll
        for (int j = 0; j < 4; j++)
            bgf[j] = *(const short8*)(sb + 16384 + (wn + j * 16 + fr) * 64 + fk2p);
        PHASE_BAR();
        __builtin_amdgcn_s_setprio(1);
#pragma unroll
        for (int i = 0; i < 4; i++)
#pragma unroll
            for (int j = 0; j < 4; j++)
                accg[i][j] = __builtin_amdgcn_mfma_f32_16x16x32_bf16(af[i], bgf[j], accg[i][j], 0, 0, 0);
        __builtin_amdgcn_s_setprio(0);
        // ---- phase B: stage B-pair of slice k+3, read buf of slice k
        if (pf) { gload16(bgP + off3, nb + 16384 + lo); gload16(buP + off3, nb + 24576 + lo); }
        short8 buf4[4];
#pragma unroll
        for (int j = 0; j < 4; j++)
            buf4[j] = *(const short8*)(sb + 24576 + (wn + j * 16 + fr) * 64 + fk2p);
        PHASE_BAR();
        __builtin_amdgcn_s_setprio(1);
#pragma unroll
        for (int i = 0; i < 4; i++)
#pragma unroll
            for (int j = 0; j < 4; j++)
                accu[i][j] = __builtin_amdgcn_mfma_f32_16x16x32_bf16(af[i], buf4[j], accu[i][j], 0, 0, 0);
        __builtin_amdgcn_s_setprio(0);
    };

    const int NK = D_MODEL / 32;  // 32 slices
    stage(0); stage(1); stage(2);
    int k = 0;
    for (; k < NK - 3; ++k) { RING_TOP(8); step(k, true); }
    RING_TOP(8); step(k, false); ++k;    // NK-3
    RING_TOP(4); step(k, false); ++k;    // NK-2
    RING_TOP(0); step(k, false);         // NK-1

    int erow = (lane >> 4) * 4;
    int ecol = lane & 15;
#pragma unroll
    for (int i = 0; i < 4; i++)
#pragma unroll
        for (int j = 0; j < 4; j++)
#pragma unroll
            for (int r = 0; r < 4; r++) {
                int row = wm + i * 16 + erow + r;
                if (row0 + row < count) {
                    float g = accg[i][j][r], u = accu[i][j][r];
                    float h = g / (1.f + expf(-g)) * u;
                    Hout[(size_t)(row0 + row) * dff + col0 + wn + j * 16 + ecol] = f2bf(h);
                }
            }
}

// ---------------------------------------------------------------- GEMM2: 256x128 tile, 2 blocks/CU
// grid (64,8): bx<16 shared (K=2048, longest-first: id=bx*8+by, 128 tiles); bx>=16 expert tile-row.
// Ring-3 of BK=32 slices (24KB: A16K|B8K) = 72KB LDS -> 2 blocks/CU (launch_bounds(512,4)),
// depth-2 prefetch, counted vmcnt. Cross-block overlap hides ring-refill bubbles.
__global__ __launch_bounds__(512, 4) void gemm2_kernel(
    const short* __restrict__ Hexp, const short* __restrict__ Hsh,
    const short* __restrict__ Wdexp,  // [16][1024][1024]
    const short* __restrict__ Wdsh,   // [1024][2048]
    float* __restrict__ oslots,       // [8192][1024]
    float* __restrict__ out,          // [4096][1024]
    const float* __restrict__ tok_w, const float* __restrict__ gate,
    const int* __restrict__ offsets, const int* __restrict__ counts,
    const int* __restrict__ tile_map, const int* __restrict__ n_tiles) {
    int bx = blockIdx.x, by = blockIdx.y;
    int count, row0, K, base, col0;
    const short* Ab; const short* B;
    bool shared_part;
    if (bx < 16) {
        int id = bx * 8 + by;          // 0..127
        row0 = (id >> 3) * 256; count = T_TOKENS; base = 0;
        Ab = Hsh; K = D_FF_SH; B = Wdsh; shared_part = true;
        col0 = (id & 7) * 128;
    } else {
        int q = bx - 16;
        if (q >= n_tiles[0]) return;
        int tm = tile_map[q];
        int e = tm >> 16; row0 = (tm & 0xffff) << 8;
        count = counts[e]; base = offsets[e];
        Ab = Hexp + (size_t)base * D_FF; K = D_FF;
        B = Wdexp + (size_t)e * D_MODEL * D_FF;
        shared_part = false;
        col0 = by * 128;
    }

    __shared__ char lds[73728];   // 3 ring slices x 24KB

    int t = threadIdx.x;
    int wave = t >> 6, lane = t & 63;
    int wm = (wave & 3) * 64, wn = (wave >> 2) * 64;
    int fr = lane & 15;
    int fk2p = ((((lane >> 4) + (fr >> 1)) & 3) << 4);
    int rA = t >> 2;
    int csrc = ((t & 3) - (t >> 3)) & 3;
    int cq = csrc * 8;
    int lo = t * 16;

    int r0c = min(row0 + rA, count - 1);
    int r1c = min(row0 + rA + 128, count - 1);
    const short* aP0 = Ab + (size_t)r0c * K + cq;
    const short* aP1 = Ab + (size_t)r1c * K + cq;
    const short* bP  = B + (size_t)(col0 + rA) * K + cq;

    float4v acc[4][4];
#pragma unroll
    for (int i = 0; i < 4; i++)
#pragma unroll
        for (int j = 0; j < 4; j++) acc[i][j] = (float4v)0.f;

    auto stage = [&](int pos, int s) {
        char* bb = lds + pos * 24576;
        int off = s * 32;
        gload16(aP0 + off, bb + lo);
        gload16(aP1 + off, bb + 8192 + lo);
        gload16(bP + off,  bb + 16384 + lo);
    };
    auto compute = [&](int pos) {
        const char* sb = lds + pos * 24576;
        short8 af[4], bf[4];
#pragma unroll
        for (int i = 0; i < 4; i++)
            af[i] = *(const short8*)(sb + (wm + i * 16 + fr) * 64 + fk2p);
#pragma unroll
        for (int j = 0; j < 4; j++)
            bf[j] = *(const short8*)(sb + 16384 + (wn + j * 16 + fr) * 64 + fk2p);
        __builtin_amdgcn_s_setprio(1);
#pragma unroll
        for (int i = 0; i < 4; i++)
#pragma unroll
            for (int j = 0; j < 4; j++)
                acc[i][j] = __builtin_amdgcn_mfma_f32_16x16x32_bf16(af[i], bf[j], acc[i][j], 0, 0, 0);
        __builtin_amdgcn_s_setprio(0);
    };

    const int NK = K / 32;        // 32 or 64
    stage(0, 0); stage(1, 1);
    int k = 0, spos = 2, cpos = 0;
    for (; k < NK - 2; ++k) {
        RING_TOP(3);               // slice k landed (3 loads/slice, 2 slices in flight)
        stage(spos, k + 2); spos = (spos == 2) ? 0 : spos + 1;
        compute(cpos);      cpos = (cpos == 2) ? 0 : cpos + 1;
    }
    RING_TOP(3); compute(cpos); cpos = (cpos == 2) ? 0 : cpos + 1; ++k;
    RING_TOP(0); compute(cpos);

    int erow = (lane >> 4) * 4;
    int ecol = lane & 15;
#pragma unroll
    for (int i = 0; i < 4; i++)
#pragma unroll
        for (int j = 0; j < 4; j++)
#pragma unroll
            for (int r = 0; r < 4; r++) {
                int row = wm + i * 16 + erow + r;
                if (row0 + row < count) {
                    float v = acc[i][j][r];
                    int col = col0 + wn + j * 16 + ecol;
                    if (!shared_part) {
                        int slot = base + row0 + row;
                        oslots[(size_t)slot * D_MODEL + col] = tok_w[slot] * v;
                    } else {
                        out[(size_t)(row0 + row) * D_MODEL + col] = gate[row0 + row] * v;
                    }
                }
            }
}

// ---------------------------------------------------------------- combine: out[t] += oslots[sA] + oslots[sB]
__global__ __launch_bounds__(256) void combine_kernel(
    float* __restrict__ out, const float* __restrict__ oslots,
    const int* __restrict__ slot_of) {
    int t = blockIdx.x;
    int sA = slot_of[t * 2], sB = slot_of[t * 2 + 1];
    int d = threadIdx.x * 4;
    float4 o = *(float4*)&out[(size_t)t * D_MODEL + d];
    float4 a = *(const float4*)&oslots[(size_t)sA * D_MODEL + d];
    float4 b = *(const float4*)&oslots[(size_t)sB * D_MODEL + d];
    o.x += a.x + b.x; o.y += a.y + b.y; o.z += a.z + b.z; o.w += a.w + b.w;
    *(float4*)&out[(size_t)t * D_MODEL + d] = o;
}

// ---------------------------------------------------------------- host
extern "C" void kernel_launch(void* const* d_in, const int* in_sizes, int n_in,
                              void* d_out, int out_size, void* d_ws, size_t ws_size,
                              hipStream_t stream) {
    const float* x     = (const float*)d_in[0];
    const float* gw    = (const float*)d_in[1];
    const float* egu   = (const float*)d_in[2];
    const float* edown = (const float*)d_in[3];
    const float* sgu   = (const float*)d_in[4];
    const float* sdown = (const float*)d_in[5];
    const float* sgate = (const float*)d_in[6];
    float* out = (float*)d_out;
    char* ws = (char*)d_ws;

    const size_t XB_OFF     = 0;
    const size_t WGU_OFF    = XB_OFF     + (size_t)4096*1024*2;
    const size_t WDOWN_OFF  = WGU_OFF    + (size_t)16*2048*1024*2;
    const size_t WSGU_OFF   = WDOWN_OFF  + (size_t)16*1024*1024*2;
    const size_t WSDOWN_OFF = WSGU_OFF   + (size_t)4096*1024*2;
    const size_t HEXP_OFF   = WSDOWN_OFF + (size_t)1024*2048*2;
    const size_t HSH_OFF    = HEXP_OFF   + (size_t)8192*1024*2;
    const size_t OSLOT_OFF  = HSH_OFF    + (size_t)4096*2048*2;
    const size_t TID_OFF    = OSLOT_OFF  + (size_t)8192*1024*4;
    const size_t TW_OFF     = TID_OFF    + 4096*2*4;
    const size_t GATE_OFF   = TW_OFF     + 4096*2*4;
    const size_t TOKL_OFF   = GATE_OFF   + 4096*4;
    const size_t TOKW_OFF   = TOKL_OFF   + 8192*4;
    const size_t SLOT_OFF   = TOKW_OFF   + 8192*4;
    const size_t CNT_OFF    = SLOT_OFF   + 8192*4;
    const size_t OFFS_OFF   = CNT_OFF    + 256;
    const size_t CUR_OFF    = OFFS_OFF   + 256;
    const size_t TMAP_OFF   = CUR_OFF    + 256;
    const size_t NT_OFF     = TMAP_OFF   + 512;

    short* xb      = (short*)(ws + XB_OFF);
    short* wgu_b   = (short*)(ws + WGU_OFF);
    short* wdown_b = (short*)(ws + WDOWN_OFF);
    short* wsgu_b  = (short*)(ws + WSGU_OFF);
    short* wsdn_b  = (short*)(ws + WSDOWN_OFF);
    short* h_exp   = (short*)(ws + HEXP_OFF);
    short* h_sh    = (short*)(ws + HSH_OFF);
    float* oslots  = (float*)(ws + OSLOT_OFF);
    int*   topk_id = (int*)(ws + TID_OFF);
    float* topk_w  = (float*)(ws + TW_OFF);
    float* gate    = (float*)(ws + GATE_OFF);
    int*   tok_l   = (int*)(ws + TOKL_OFF);
    float* tok_w   = (float*)(ws + TOKW_OFF);
    int*   slot_of = (int*)(ws + SLOT_OFF);
    int*   counts  = (int*)(ws + CNT_OFF);
    int*   offsets = (int*)(ws + OFFS_OFF);
    int*   cursor  = (int*)(ws + CUR_OFF);
    int*   tmap    = (int*)(ws + TMAP_OFF);
    int*   ntiles  = (int*)(ws + NT_OFF);

    hipMemsetAsync(counts, 0, 64, stream);

    convert_all_kernel<<<27648, 256, 0, stream>>>(egu, wgu_b, edown, wdown_b,
                                                  sgu, wsgu_b, sdown, wsdn_b);
    router_kernel<<<256, 256, 0, stream>>>(x, gw, sgate, xb, topk_id, topk_w, gate, counts);
    offsets_kernel<<<1, 64, 0, stream>>>(counts, offsets, cursor, tmap, ntiles);
    scatter_kernel<<<T_TOKENS / 256, 256, 0, stream>>>(topk_id, topk_w, cursor, tok_l, tok_w, slot_of);

    gemm1_kernel<<<dim3(MAX_T256 + 32, 8), 512, 0, stream>>>(
        xb, wgu_b, wsgu_b, h_exp, h_sh, tok_l, offsets, counts, tmap, ntiles);

    gemm2_kernel<<<dim3(64, 8), 512, 0, stream>>>(
        h_exp, h_sh, wdown_b, wsdn_b, oslots, out, tok_w, gate, offsets, counts, tmap, ntiles);

    combine_kernel<<<T_TOKENS, 256, 0, stream>>>(out, oslots, slot_of);
}

// Round 4
// 589.259 us; speedup vs baseline: 1.0993x; 1.0063x over previous
//
#include <hip/hip_runtime.h>
#include <hip/hip_bf16.h>

#define T_TOKENS 4096
#define D_MODEL  1024
#define N_EXP    16
#define D_FF     1024
#define D_FF_SH  2048
#define MAX_T256 48   // sum ceil(count_e/256) <= 8192/256 + 16 = 48

typedef __attribute__((ext_vector_type(8))) short short8;
typedef __attribute__((ext_vector_type(4))) float float4v;

__device__ __forceinline__ short f2bf(float f) {
    union { float f; unsigned u; } c; c.f = f;
    unsigned u = c.u + 0x7fffu + ((c.u >> 16) & 1u);
    return (short)(u >> 16);
}

// async global->LDS, 16B per lane; LDS dest = wave-uniform base + lane*16.
__device__ __forceinline__ void gload16(const void* g, void* l) {
    __builtin_amdgcn_global_load_lds(
        (const __attribute__((address_space(1))) void*)g,
        (__attribute__((address_space(3))) void*)l, 16, 0, 0);
}

// counted-vmcnt ring step top (gemm2): drain own slice-k loads + own LDS reads, then barrier.
#define RING_TOP(VM) do { \
    asm volatile("s_waitcnt vmcnt(" #VM ") lgkmcnt(0)" ::: "memory"); \
    __builtin_amdgcn_s_barrier(); \
} while (0)

// ---------------------------------------------------------------- convert (all 4 weights, one dispatch)
__global__ __launch_bounds__(256) void convert_all_kernel(
    const float* __restrict__ s0, short* __restrict__ d0,   // egu   33554432
    const float* __restrict__ s1, short* __restrict__ d1,   // edown 16777216
    const float* __restrict__ s2, short* __restrict__ d2,   // sgu    4194304
    const float* __restrict__ s3, short* __restrict__ d3) { // sdown  2097152
    int c = blockIdx.x * 256 + threadIdx.x;   // chunk of 8 elements
    const float* s; short* d; int off;
    if      (c < 4194304) { s = s0; d = d0; off = c; }
    else if (c < 6291456) { s = s1; d = d1; off = c - 4194304; }
    else if (c < 6815744) { s = s2; d = d2; off = c - 6291456; }
    else                  { s = s3; d = d3; off = c - 6815744; }
    size_t i = (size_t)off * 8;
    float4 a = *(const float4*)(s + i);
    float4 b = *(const float4*)(s + i + 4);
    union { short sh[8]; int4 v; } p;
    p.sh[0] = f2bf(a.x); p.sh[1] = f2bf(a.y); p.sh[2] = f2bf(a.z); p.sh[3] = f2bf(a.w);
    p.sh[4] = f2bf(b.x); p.sh[5] = f2bf(b.y); p.sh[6] = f2bf(b.z); p.sh[7] = f2bf(b.w);
    *(int4*)(d + i) = p.v;
}

// ---------------------------------------------------------------- router (fp32 exact, LDS-staged weights)
__global__ __launch_bounds__(256) void router_kernel(
    const float* __restrict__ x, const float* __restrict__ gw, const float* __restrict__ sgw,
    short* __restrict__ xb, int* __restrict__ topk_id, float* __restrict__ topk_w,
    float* __restrict__ gate, int* __restrict__ counts) {
    __shared__ float gwl[17 * 1024];   // 69632 B
    int tid = threadIdx.x;
#pragma unroll
    for (int i = 0; i < 16; i++)
        *(float4*)&gwl[tid * 4 + i * 1024] = *(const float4*)&gw[tid * 4 + i * 1024];
    *(float4*)&gwl[16384 + tid * 4] = *(const float4*)&sgw[tid * 4];
    __syncthreads();

    int wave = tid >> 6, lane = tid & 63;
    int t0 = blockIdx.x * 16 + wave * 4;

    float acc[4][17];
#pragma unroll
    for (int tt = 0; tt < 4; tt++)
#pragma unroll
        for (int e = 0; e < 17; e++) acc[tt][e] = 0.f;

#pragma unroll
    for (int i = 0; i < 4; i++) {
        int d = lane * 4 + i * 256;
        float4 xv[4];
#pragma unroll
        for (int tt = 0; tt < 4; tt++) {
            xv[tt] = *(const float4*)&x[(size_t)(t0 + tt) * D_MODEL + d];
            union { short sh[4]; int2 v; } p;
            p.sh[0] = f2bf(xv[tt].x); p.sh[1] = f2bf(xv[tt].y);
            p.sh[2] = f2bf(xv[tt].z); p.sh[3] = f2bf(xv[tt].w);
            *(int2*)&xb[(size_t)(t0 + tt) * D_MODEL + d] = p.v;
        }
#pragma unroll
        for (int e = 0; e < 17; e++) {
            float4 g = *(const float4*)&gwl[e * 1024 + d];
#pragma unroll
            for (int tt = 0; tt < 4; tt++)
                acc[tt][e] += xv[tt].x * g.x + xv[tt].y * g.y + xv[tt].z * g.z + xv[tt].w * g.w;
        }
    }

#pragma unroll
    for (int tt = 0; tt < 4; tt++)
#pragma unroll
        for (int e = 0; e < 17; e++)
            for (int off = 32; off; off >>= 1) acc[tt][e] += __shfl_xor(acc[tt][e], off);

    if (lane == 0) {
#pragma unroll
        for (int tt = 0; tt < 4; tt++) {
            int t = t0 + tt;
            float v1 = -1e30f, v2 = -1e30f; int i1 = 0, i2 = 0;
#pragma unroll
            for (int e = 0; e < 16; e++) {
                float v = acc[tt][e];
                if (v > v1) { v2 = v1; i2 = i1; v1 = v; i1 = e; }
                else if (v > v2) { v2 = v; i2 = e; }
            }
            float e2 = expf(v2 - v1);
            float s = 1.f + e2;
            topk_id[t * 2] = i1; topk_id[t * 2 + 1] = i2;
            topk_w[t * 2] = 1.f / s; topk_w[t * 2 + 1] = e2 / s;
            gate[t] = 1.f / (1.f + expf(-acc[tt][16]));
            atomicAdd(&counts[i1], 1); atomicAdd(&counts[i2], 1);
        }
    }
}

// ---------------------------------------------------------------- offsets + live 256-row-tile map
__global__ void offsets_kernel(const int* __restrict__ counts, int* __restrict__ offsets,
                               int* __restrict__ cursor, int* __restrict__ tile_map,
                               int* __restrict__ n_tiles) {
    if (threadIdx.x == 0) {
        int off = 0, nt = 0;
        for (int e = 0; e < N_EXP; e++) {
            offsets[e] = off; cursor[e] = off;
            int c = counts[e];
            for (int r = 0; r < c; r += 256) tile_map[nt++] = (e << 16) | (r >> 8);
            off += c;
        }
        n_tiles[0] = nt;
    }
}

__global__ __launch_bounds__(256) void scatter_kernel(
    const int* __restrict__ topk_id, const float* __restrict__ topk_w,
    int* __restrict__ cursor, int* __restrict__ tok_list, float* __restrict__ tok_w,
    int* __restrict__ slot_of) {
    int t = blockIdx.x * 256 + threadIdx.x;
#pragma unroll
    for (int k = 0; k < 2; k++) {
        int e = topk_id[t * 2 + k];
        int pos = atomicAdd(&cursor[e], 1);
        tok_list[pos] = t;
        tok_w[pos] = topk_w[t * 2 + k];
        slot_of[t * 2 + k] = pos;
    }
}

// ---------------------------------------------------------------- GEMM1: cross-step-pipelined, 1 barrier/K-step
// grid (80,8): bx<48 expert tile-row (by=col 0..7); bx 48..79 -> shared id=(bx-48)*8+by (256 tiles).
// Ring-4 of BK=32 slices (32KB: A16K|Bg8K|Bu8K), depth-3 prefetch.
// Step k: [stage(k+3); read buf(k); 16 MFMA accg(k)] -> vmcnt(8)+lgkm(0)+barrier ->
//         [read af/bgf(k+1); 16 MFMA accu(k)].  Fragments for slice k+1 read one step
//         ahead (named A/B reg sets, unroll-by-2); the MFMA clusters cover all LDS latency.
// Hazards: slice-(k+1) reads behind vmcnt+barrier (all waves' DMAs landed); stage(k+3)
// overwrites slot (k-1)&3 whose reads drained at mid-barrier(k-1) lgkmcnt(0).
__global__ __launch_bounds__(512, 2) void gemm1_kernel(
    const short* __restrict__ xb,
    const short* __restrict__ Wexp,   // [16][2048][1024]
    const short* __restrict__ Wsh,    // [4096][1024]
    short* __restrict__ Hexp,         // [8192][1024]
    short* __restrict__ Hsh,          // [4096][2048]
    const int* __restrict__ tok_list,
    const int* __restrict__ offsets, const int* __restrict__ counts,
    const int* __restrict__ tile_map, const int* __restrict__ n_tiles) {
    int bx = blockIdx.x, by = blockIdx.y;
    int count, row0, dff, col0;
    const int* idx = nullptr;
    const short* Wg; short* Hout;
    if (bx < MAX_T256) {
        if (bx >= n_tiles[0]) return;
        int tm = tile_map[bx];
        int e = tm >> 16; row0 = (tm & 0xffff) << 8;
        count = counts[e];
        int base = offsets[e];
        idx = tok_list + base;
        Wg = Wexp + (size_t)e * 2 * D_FF * D_MODEL;
        Hout = Hexp + (size_t)base * D_FF;
        dff = D_FF;
        col0 = by * 128;
    } else {
        int id = (bx - MAX_T256) * 8 + by;   // 0..255
        row0 = (id >> 4) * 256; count = T_TOKENS;
        Wg = Wsh; Hout = Hsh; dff = D_FF_SH;
        col0 = (id & 15) * 128;
    }
    const short* Wu = Wg + (size_t)dff * D_MODEL;

    __shared__ char lds[131072];   // 4 ring slices x 32KB

    int t = threadIdx.x;
    int wave = t >> 6, lane = t & 63;
    int wm = (wave & 3) * 64, wn = (wave >> 2) * 64;
    int fr = lane & 15;
    int fk2p = ((((lane >> 4) + (fr >> 1)) & 3) << 4);   // rotated read chunk
    int rA = t >> 2;                      // 0..127
    int csrc = ((t & 3) - (t >> 3)) & 3;  // inverse-rotated source chunk
    int cq = csrc * 8;                    // shorts
    int lo = t * 16;                      // linear LDS dest

    int r0c = min(row0 + rA, count - 1);
    int r1c = min(row0 + rA + 128, count - 1);
    int g0 = idx ? idx[r0c] : r0c;
    int g1 = idx ? idx[r1c] : r1c;
    const short* aP0 = xb + (size_t)g0 * D_MODEL + cq;
    const short* aP1 = xb + (size_t)g1 * D_MODEL + cq;
    const short* bgP = Wg + (size_t)(col0 + rA) * D_MODEL + cq;
    const short* buP = Wu + (size_t)(col0 + rA) * D_MODEL + cq;

    float4v accg[4][4], accu[4][4];
#pragma unroll
    for (int i = 0; i < 4; i++)
#pragma unroll
        for (int j = 0; j < 4; j++) { accg[i][j] = (float4v)0.f; accu[i][j] = (float4v)0.f; }

    auto stage = [&](int s) {
        char* base = lds + (s & 3) * 32768;
        int off = s * 32;                 // shorts
        gload16(aP0 + off, base + lo);
        gload16(aP1 + off, base + 8192 + lo);
        gload16(bgP + off, base + 16384 + lo);
        gload16(buP + off, base + 24576 + lo);
    };

    short8 afA[4], bgfA[4], bufA[4];
    short8 afB[4], bgfB[4], bufB[4];

// One K-step. CUR regs hold af/bgf(kk); reads buf(kk) at top (covered by accg cluster);
// after vmcnt+barrier reads af/bgf(kk+1) into NXT (covered by accu cluster).
#define G1_STEP(kk, DOSTAGE, WAITSTR, DOREAD, afC, bgfC, bufC, afN, bgfN) do { \
    const char* sb_ = lds + ((kk) & 3) * 32768; \
    if (DOSTAGE) stage((kk) + 3); \
    _Pragma("unroll") \
    for (int j_ = 0; j_ < 4; j_++) \
        bufC[j_] = *(const short8*)(sb_ + 24576 + (wn + j_ * 16 + fr) * 64 + fk2p); \
    __builtin_amdgcn_s_setprio(1); \
    _Pragma("unroll") \
    for (int i_ = 0; i_ < 4; i_++) \
        _Pragma("unroll") \
        for (int j_ = 0; j_ < 4; j_++) \
            accg[i_][j_] = __builtin_amdgcn_mfma_f32_16x16x32_bf16(afC[i_], bgfC[j_], accg[i_][j_], 0, 0, 0); \
    __builtin_amdgcn_s_setprio(0); \
    asm volatile("s_waitcnt " WAITSTR ::: "memory"); \
    asm volatile("s_barrier" ::: "memory"); \
    __builtin_amdgcn_sched_barrier(0); \
    if (DOREAD) { \
        const char* nb_ = lds + (((kk) + 1) & 3) * 32768; \
        _Pragma("unroll") \
        for (int i_ = 0; i_ < 4; i_++) \
            afN[i_] = *(const short8*)(nb_ + (wm + i_ * 16 + fr) * 64 + fk2p); \
        _Pragma("unroll") \
        for (int j_ = 0; j_ < 4; j_++) \
            bgfN[j_] = *(const short8*)(nb_ + 16384 + (wn + j_ * 16 + fr) * 64 + fk2p); \
    } \
    __builtin_amdgcn_s_setprio(1); \
    _Pragma("unroll") \
    for (int i_ = 0; i_ < 4; i_++) \
        _Pragma("unroll") \
        for (int j_ = 0; j_ < 4; j_++) \
            accu[i_][j_] = __builtin_amdgcn_mfma_f32_16x16x32_bf16(afC[i_], bufC[j_], accu[i_][j_], 0, 0, 0); \
    __builtin_amdgcn_s_setprio(0); \
} while (0)

    // prologue: fill ring depth-3, land slice 0 everywhere, preload af/bgf(0) -> set A
    stage(0); stage(1); stage(2);
    asm volatile("s_waitcnt vmcnt(8)" ::: "memory");
    asm volatile("s_barrier" ::: "memory");
    __builtin_amdgcn_sched_barrier(0);
#pragma unroll
    for (int i = 0; i < 4; i++)
        afA[i] = *(const short8*)(lds + (wm + i * 16 + fr) * 64 + fk2p);
#pragma unroll
    for (int j = 0; j < 4; j++)
        bgfA[j] = *(const short8*)(lds + 16384 + (wn + j * 16 + fr) * 64 + fk2p);

    // main loop: k = 0..27 (14 unroll-by-2 pairs), then peeled tail 28..31
    for (int k = 0; k < 28; k += 2) {
        G1_STEP(k,     true, "vmcnt(8) lgkmcnt(0)", true, afA, bgfA, bufA, afB, bgfB);
        G1_STEP(k + 1, true, "vmcnt(8) lgkmcnt(0)", true, afB, bgfB, bufB, afA, bgfA);
    }
    G1_STEP(28, true,  "vmcnt(8) lgkmcnt(0)", true,  afA, bgfA, bufA, afB, bgfB);
    G1_STEP(29, false, "vmcnt(4) lgkmcnt(0)", true,  afB, bgfB, bufB, afA, bgfA);
    G1_STEP(30, false, "vmcnt(0) lgkmcnt(0)", true,  afA, bgfA, bufA, afB, bgfB);
    G1_STEP(31, false, "lgkmcnt(0)",          false, afB, bgfB, bufB, afA, bgfA);
#undef G1_STEP

    int erow = (lane >> 4) * 4;
    int ecol = lane & 15;
#pragma unroll
    for (int i = 0; i < 4; i++)
#pragma unroll
        for (int j = 0; j < 4; j++)
#pragma unroll
            for (int r = 0; r < 4; r++) {
                int row = wm + i * 16 + erow + r;
                if (row0 + row < count) {
                    float g = accg[i][j][r], u = accu[i][j][r];
                    float h = g / (1.f + expf(-g)) * u;
                    Hout[(size_t)(row0 + row) * dff + col0 + wn + j * 16 + ecol] = f2bf(h);
                }
            }
}

// ---------------------------------------------------------------- GEMM2: 256x128 tile, 2 blocks/CU (R3, unchanged)
// grid (64,8): bx<16 shared (K=2048, longest-first: id=bx*8+by, 128 tiles); bx>=16 expert tile-row.
// Ring-3 of BK=32 slices (24KB: A16K|B8K) = 72KB LDS -> 2 blocks/CU (launch_bounds(512,4)),
// depth-2 prefetch, counted vmcnt. Cross-block overlap hides ring-refill bubbles.
__global__ __launch_bounds__(512, 4) void gemm2_kernel(
    const short* __restrict__ Hexp, const short* __restrict__ Hsh,
    const short* __restrict__ Wdexp,  // [16][1024][1024]
    const short* __restrict__ Wdsh,   // [1024][2048]
    float* __restrict__ oslots,       // [8192][1024]
    float* __restrict__ out,          // [4096][1024]
    const float* __restrict__ tok_w, const float* __restrict__ gate,
    const int* __restrict__ offsets, const int* __restrict__ counts,
    const int* __restrict__ tile_map, const int* __restrict__ n_tiles) {
    int bx = blockIdx.x, by = blockIdx.y;
    int count, row0, K, base, col0;
    const short* Ab; const short* B;
    bool shared_part;
    if (bx < 16) {
        int id = bx * 8 + by;          // 0..127
        row0 = (id >> 3) * 256; count = T_TOKENS; base = 0;
        Ab = Hsh; K = D_FF_SH; B = Wdsh; shared_part = true;
        col0 = (id & 7) * 128;
    } else {
        int q = bx - 16;
        if (q >= n_tiles[0]) return;
        int tm = tile_map[q];
        int e = tm >> 16; row0 = (tm & 0xffff) << 8;
        count = counts[e]; base = offsets[e];
        Ab = Hexp + (size_t)base * D_FF; K = D_FF;
        B = Wdexp + (size_t)e * D_MODEL * D_FF;
        shared_part = false;
        col0 = by * 128;
    }

    __shared__ char lds[73728];   // 3 ring slices x 24KB

    int t = threadIdx.x;
    int wave = t >> 6, lane = t & 63;
    int wm = (wave & 3) * 64, wn = (wave >> 2) * 64;
    int fr = lane & 15;
    int fk2p = ((((lane >> 4) + (fr >> 1)) & 3) << 4);
    int rA = t >> 2;
    int csrc = ((t & 3) - (t >> 3)) & 3;
    int cq = csrc * 8;
    int lo = t * 16;

    int r0c = min(row0 + rA, count - 1);
    int r1c = min(row0 + rA + 128, count - 1);
    const short* aP0 = Ab + (size_t)r0c * K + cq;
    const short* aP1 = Ab + (size_t)r1c * K + cq;
    const short* bP  = B + (size_t)(col0 + rA) * K + cq;

    float4v acc[4][4];
#pragma unroll
    for (int i = 0; i < 4; i++)
#pragma unroll
        for (int j = 0; j < 4; j++) acc[i][j] = (float4v)0.f;

    auto stage = [&](int pos, int s) {
        char* bb = lds + pos * 24576;
        int off = s * 32;
        gload16(aP0 + off, bb + lo);
        gload16(aP1 + off, bb + 8192 + lo);
        gload16(bP + off,  bb + 16384 + lo);
    };
    auto compute = [&](int pos) {
        const char* sb = lds + pos * 24576;
        short8 af[4], bf[4];
#pragma unroll
        for (int i = 0; i < 4; i++)
            af[i] = *(const short8*)(sb + (wm + i * 16 + fr) * 64 + fk2p);
#pragma unroll
        for (int j = 0; j < 4; j++)
            bf[j] = *(const short8*)(sb + 16384 + (wn + j * 16 + fr) * 64 + fk2p);
        __builtin_amdgcn_s_setprio(1);
#pragma unroll
        for (int i = 0; i < 4; i++)
#pragma unroll
            for (int j = 0; j < 4; j++)
                acc[i][j] = __builtin_amdgcn_mfma_f32_16x16x32_bf16(af[i], bf[j], acc[i][j], 0, 0, 0);
        __builtin_amdgcn_s_setprio(0);
    };

    const int NK = K / 32;        // 32 or 64
    stage(0, 0); stage(1, 1);
    int k = 0, spos = 2, cpos = 0;
    for (; k < NK - 2; ++k) {
        RING_TOP(3);               // slice k landed (3 loads/slice, 2 slices in flight)
        stage(spos, k + 2); spos = (spos == 2) ? 0 : spos + 1;
        compute(cpos);      cpos = (cpos == 2) ? 0 : cpos + 1;
    }
    RING_TOP(3); compute(cpos); cpos = (cpos == 2) ? 0 : cpos + 1; ++k;
    RING_TOP(0); compute(cpos);

    int erow = (lane >> 4) * 4;
    int ecol = lane & 15;
#pragma unroll
    for (int i = 0; i < 4; i++)
#pragma unroll
        for (int j = 0; j < 4; j++)
#pragma unroll
            for (int r = 0; r < 4; r++) {
                int row = wm + i * 16 + erow + r;
                if (row0 + row < count) {
                    float v = acc[i][j][r];
                    int col = col0 + wn + j * 16 + ecol;
                    if (!shared_part) {
                        int slot = base + row0 + row;
                        oslots[(size_t)slot * D_MODEL + col] = tok_w[slot] * v;
                    } else {
                        out[(size_t)(row0 + row) * D_MODEL + col] = gate[row0 + row] * v;
                    }
                }
            }
}

// ---------------------------------------------------------------- combine: out[t] += oslots[sA] + oslots[sB]
__global__ __launch_bounds__(256) void combine_kernel(
    float* __restrict__ out, const float* __restrict__ oslots,
    const int* __restrict__ slot_of) {
    int t = blockIdx.x;
    int sA = slot_of[t * 2], sB = slot_of[t * 2 + 1];
    int d = threadIdx.x * 4;
    float4 o = *(float4*)&out[(size_t)t * D_MODEL + d];
    float4 a = *(const float4*)&oslots[(size_t)sA * D_MODEL + d];
    float4 b = *(const float4*)&oslots[(size_t)sB * D_MODEL + d];
    o.x += a.x + b.x; o.y += a.y + b.y; o.z += a.z + b.z; o.w += a.w + b.w;
    *(float4*)&out[(size_t)t * D_MODEL + d] = o;
}

// ---------------------------------------------------------------- host
extern "C" void kernel_launch(void* const* d_in, const int* in_sizes, int n_in,
                              void* d_out, int out_size, void* d_ws, size_t ws_size,
                              hipStream_t stream) {
    const float* x     = (const float*)d_in[0];
    const float* gw    = (const float*)d_in[1];
    const float* egu   = (const float*)d_in[2];
    const float* edown = (const float*)d_in[3];
    const float* sgu   = (const float*)d_in[4];
    const float* sdown = (const float*)d_in[5];
    const float* sgate = (const float*)d_in[6];
    float* out = (float*)d_out;
    char* ws = (char*)d_ws;

    const size_t XB_OFF     = 0;
    const size_t WGU_OFF    = XB_OFF     + (size_t)4096*1024*2;
    const size_t WDOWN_OFF  = WGU_OFF    + (size_t)16*2048*1024*2;
    const size_t WSGU_OFF   = WDOWN_OFF  + (size_t)16*1024*1024*2;
    const size_t WSDOWN_OFF = WSGU_OFF   + (size_t)4096*1024*2;
    const size_t HEXP_OFF   = WSDOWN_OFF + (size_t)1024*2048*2;
    const size_t HSH_OFF    = HEXP_OFF   + (size_t)8192*1024*2;
    const size_t OSLOT_OFF  = HSH_OFF    + (size_t)4096*2048*2;
    const size_t TID_OFF    = OSLOT_OFF  + (size_t)8192*1024*4;
    const size_t TW_OFF     = TID_OFF    + 4096*2*4;
    const size_t GATE_OFF   = TW_OFF     + 4096*2*4;
    const size_t TOKL_OFF   = GATE_OFF   + 4096*4;
    const size_t TOKW_OFF   = TOKL_OFF   + 8192*4;
    const size_t SLOT_OFF   = TOKW_OFF   + 8192*4;
    const size_t CNT_OFF    = SLOT_OFF   + 8192*4;
    const size_t OFFS_OFF   = CNT_OFF    + 256;
    const size_t CUR_OFF    = OFFS_OFF   + 256;
    const size_t TMAP_OFF   = CUR_OFF    + 256;
    const size_t NT_OFF     = TMAP_OFF   + 512;

    short* xb      = (short*)(ws + XB_OFF);
    short* wgu_b   = (short*)(ws + WGU_OFF);
    short* wdown_b = (short*)(ws + WDOWN_OFF);
    short* wsgu_b  = (short*)(ws + WSGU_OFF);
    short* wsdn_b  = (short*)(ws + WSDOWN_OFF);
    short* h_exp   = (short*)(ws + HEXP_OFF);
    short* h_sh    = (short*)(ws + HSH_OFF);
    float* oslots  = (float*)(ws + OSLOT_OFF);
    int*   topk_id = (int*)(ws + TID_OFF);
    float* topk_w  = (float*)(ws + TW_OFF);
    float* gate    = (float*)(ws + GATE_OFF);
    int*   tok_l   = (int*)(ws + TOKL_OFF);
    float* tok_w   = (float*)(ws + TOKW_OFF);
    int*   slot_of = (int*)(ws + SLOT_OFF);
    int*   counts  = (int*)(ws + CNT_OFF);
    int*   offsets = (int*)(ws + OFFS_OFF);
    int*   cursor  = (int*)(ws + CUR_OFF);
    int*   tmap    = (int*)(ws + TMAP_OFF);
    int*   ntiles  = (int*)(ws + NT_OFF);

    hipMemsetAsync(counts, 0, 64, stream);

    convert_all_kernel<<<27648, 256, 0, stream>>>(egu, wgu_b, edown, wdown_b,
                                                  sgu, wsgu_b, sdown, wsdn_b);
    router_kernel<<<256, 256, 0, stream>>>(x, gw, sgate, xb, topk_id, topk_w, gate, counts);
    offsets_kernel<<<1, 64, 0, stream>>>(counts, offsets, cursor, tmap, ntiles);
    scatter_kernel<<<T_TOKENS / 256, 256, 0, stream>>>(topk_id, topk_w, cursor, tok_l, tok_w, slot_of);

    gemm1_kernel<<<dim3(MAX_T256 + 32, 8), 512, 0, stream>>>(
        xb, wgu_b, wsgu_b, h_exp, h_sh, tok_l, offsets, counts, tmap, ntiles);

    gemm2_kernel<<<dim3(64, 8), 512, 0, stream>>>(
        h_exp, h_sh, wdown_b, wsdn_b, oslots, out, tok_w, gate, offsets, counts, tmap, ntiles);

    combine_kernel<<<T_TOKENS, 256, 0, stream>>>(out, oslots, slot_of);
}